// Round 1
// 313.070 us; speedup vs baseline: 1.3924x; 1.3924x over previous
//
#include <hip/hip_runtime.h>
#include <stdint.h>

// FFN: x[16384,1024] -> relu(x@W1^T+b1)[16384,4096] -> q_e4m3 -> @W2^T+b2 -> q_e5m10
// Round 3: both GEMMs ported to the 256x256/BK=64 8-wave phase-interleaved
// counted-vmcnt template (T1 XCD swizzle + T2 LDS XOR swizzle + T3/T4 phases
// with counted vmcnt + T5 setprio). Numerics identical to round 2 (same MFMA
// sequence, same ascending-k accumulation order, same epilogues).
//
// Schedule per K-tile t (4 phases), computing buf c=t&1, prefetching t+1 -> 1-c:
//   ph0: ds_read B(t)[8xb128] + A(t) mg0[4]; stage B(t+1) r0,r1; bar; MFMA16; bar
//   ph1: ds_read A(t) mg1;                  stage B(t+1) r2,r3; bar; MFMA16; vmcnt(4); bar
//   ph2: ds_read A(t) mg2;                  stage A(t+1) r0,r2; bar; MFMA16; bar
//   ph3: ds_read A(t) mg3;                  stage A(t+1) r1,r3; bar; MFMA16; vmcnt(2); bar
// Invariant at tile entry: exactly 2 outstanding loads = A(t) rounds 1,3
// (needed first at ph2, guaranteed by ph1's vmcnt(4)+barrier). Never vmcnt(0)
// mid-loop; last tile (no prefetch) uses vmcnt(0) to drain.
// LDS swizzle: 16B-slot index ^= (row&7); source-side pre-swizzle (linear gl16
// dest) + read-side XOR (reduces to per-lane constant fr&7). 8-way -> 2-way (free).

#define M_TOT 16384
#define D_DIM 1024
#define H_DIM 4096

typedef _Float16 f16x8 __attribute__((ext_vector_type(8)));
typedef _Float16 f16x4 __attribute__((ext_vector_type(4)));
typedef float f32x4 __attribute__((ext_vector_type(4)));

// global -> LDS direct copy, 16B per lane. LDS dest = wave-uniform base + lane*16.
__device__ __forceinline__ void gl16(const void* g, void* l) {
    __builtin_amdgcn_global_load_lds(
        (const __attribute__((address_space(1))) unsigned int*)(uintptr_t)g,
        (__attribute__((address_space(3))) unsigned int*)(unsigned int)(uintptr_t)l,
        16, 0, 0);
}

// Reference float_quantize(x, exp=4, man=3): bias=7, min normal exp -6,
// subnormal step 2^-9, RNE. (Overflow->inf unreachable here.)
__device__ __forceinline__ float q_e4m3_val(float x) {
    uint32_t bx = __float_as_uint(x);
    float ax = __uint_as_float(bx & 0x7fffffffu);
    if (ax == 0.0f) return x;
    int e = (int)((bx >> 23) & 0xffu) - 127;
    if (e < -6) e = -6;
    float scale = __uint_as_float((uint32_t)(e - 3 + 127) << 23);  // 2^(e-3), exact
    return rintf(x / scale) * scale;
}

// ---- pre-pass: fp32 -> f16 (RNE), vectorized x4 ----
__global__ __launch_bounds__(256) void cvt_f16_kernel(
    const float* __restrict__ in, _Float16* __restrict__ out, int n4)
{
    int i = blockIdx.x * 256 + threadIdx.x;
    if (i >= n4) return;
    float4 v = reinterpret_cast<const float4*>(in)[i];
    f16x4 hv = {(_Float16)v.x, (_Float16)v.y, (_Float16)v.z, (_Float16)v.w};
    reinterpret_cast<f16x4*>(out)[i] = hv;
}

// ---- pre-pass: fp32 -> e4m3 value stored as f16 (exactly representable) ----
__global__ __launch_bounds__(256) void quant_e4m3_kernel(
    const float* __restrict__ in, _Float16* __restrict__ outq, int n4)
{
    int i = blockIdx.x * 256 + threadIdx.x;
    if (i >= n4) return;
    float4 v = reinterpret_cast<const float4*>(in)[i];
    f16x4 q = {(_Float16)q_e4m3_val(v.x), (_Float16)q_e4m3_val(v.y),
               (_Float16)q_e4m3_val(v.z), (_Float16)q_e4m3_val(v.w)};
    reinterpret_cast<f16x4*>(outq)[i] = q;
}

// ---- unified 256x256 GEMM, NT (A[M,K], B[N,K] row-major), f16 MFMA fp32 acc ----
// G1=true : epilogue = +bias, relu, q_e4m3, store f16
// G1=false: epilogue = +f16(bias), f16-roundtrip, store fp32
template<int K, int N, bool G1>
__global__ __launch_bounds__(512) void gemm_ffn(
    const _Float16* __restrict__ A, const _Float16* __restrict__ B,
    const float* __restrict__ bias, void* __restrict__ Cv)
{
    // 2 dbuf x [256 rows][64 K] f16 each for A and B: 128 KiB total.
    __shared__ _Float16 sA[2 * 16384];
    __shared__ _Float16 sB[2 * 16384];

    const int tid  = threadIdx.x;
    const int lane = tid & 63;
    const int w    = tid >> 6;            // 8 waves: 2(M) x 4(N)
    const int wr   = w >> 2, wc = w & 3;  // per-wave C: 128 rows x 64 cols
    const int fr   = lane & 15, kq = lane >> 4;

    // T1: bijective XCD-chunked block swizzle (nwg % 8 == 0 for both GEMMs)
    constexpr int NBX = N / 256;
    constexpr int NWG = (M_TOT / 256) * NBX;
    constexpr int CPX = NWG / 8;
    int bid = blockIdx.y * NBX + blockIdx.x;
    bid = (bid & 7) * CPX + (bid >> 3);
    const int n0 = (bid % NBX) * 256;
    const int m0 = (bid / NBX) * 256;

    // staging: thread t covers LDS bytes t*16 of each 8KB round (64 rows x 128B).
    // source pre-swizzle: 16B-slot ^= (row & 7)  (involution, matches read XOR)
    const int srow = tid >> 3;                       // 0..63 row-in-round
    const int sseg = (tid & 7) ^ (srow & 7);         // swizzled 16B slot
    const _Float16* gA = A + (size_t)(m0 + srow) * K + sseg * 8;
    const _Float16* gB = B + (size_t)(n0 + srow) * K + sseg * 8;
    const int ldsw = w * 512;                        // wave offset in a round (f16)
    const size_t R1 = (size_t)64 * K, R2 = (size_t)128 * K, R3 = (size_t)192 * K;

    // fragment reads: row*64 + ((ks*4+kq) ^ (row&7))*8 ; row&7 == fr&7 always
    const int xorv = fr & 7;
    const int cA0 = (kq ^ xorv) * 8;         // ks=0 slot (elements)
    const int cA1 = ((kq + 4) ^ xorv) * 8;   // ks=1 slot
    const int aRow = wr * 128 + fr;
    const int bRow = wc * 64 + fr;

    f32x4 acc[8][4];
#pragma unroll
    for (int i = 0; i < 8; i++)
#pragma unroll
        for (int j = 0; j < 4; j++) acc[i][j] = (f32x4){0.f, 0.f, 0.f, 0.f};

    f16x8 bfr[4][2];

    constexpr int NK = K / 64;

    // prologue: stage tile 0 into buf0. Issue order must match in-loop order:
    // B r0,r1,r2,r3, A r0,r2, A r1,r3  -> vmcnt(2) leaves A r1,r3 in flight.
    gl16(gB,      sB + ldsw);
    gl16(gB + R1, sB + 4096 + ldsw);
    gl16(gB + R2, sB + 8192 + ldsw);
    gl16(gB + R3, sB + 12288 + ldsw);
    gl16(gA,      sA + ldsw);
    gl16(gA + R2, sA + 8192 + ldsw);
    gl16(gA + R1, sA + 4096 + ldsw);
    gl16(gA + R3, sA + 12288 + ldsw);
    asm volatile("s_waitcnt vmcnt(2)" ::: "memory");
    __builtin_amdgcn_s_barrier();
    asm volatile("" ::: "memory");

    for (int t = 0; t < NK; ++t) {
        const int c = t & 1;
        const _Float16* sAc = sA + c * 16384;
        const _Float16* sBc = sB + c * 16384;
        _Float16* sAn = sA + (c ^ 1) * 16384;
        _Float16* sBn = sB + (c ^ 1) * 16384;
        const bool pref = (t + 1 < NK);
        const _Float16* gAn = gA + (size_t)(t + 1) * 64;
        const _Float16* gBn = gB + (size_t)(t + 1) * 64;

#pragma unroll
        for (int p = 0; p < 4; ++p) {
            // ds_read this phase's A row-quadrant (+ all B frags at p==0)
            f16x8 afr[2][2];
#pragma unroll
            for (int ii = 0; ii < 2; ii++) {
                const _Float16* ra = sAc + (aRow + (2 * p + ii) * 16) * 64;
                afr[ii][0] = *(const f16x8*)(ra + cA0);
                afr[ii][1] = *(const f16x8*)(ra + cA1);
            }
            if (p == 0) {
#pragma unroll
                for (int j = 0; j < 4; j++) {
                    const _Float16* rb = sBc + (bRow + j * 16) * 64;
                    bfr[j][0] = *(const f16x8*)(rb + cA0);
                    bfr[j][1] = *(const f16x8*)(rb + cA1);
                }
            }
            // stage 2 rounds of next tile (block-uniform predicate)
            if (pref) {
                if (p == 0) { gl16(gBn,      sBn + ldsw);
                              gl16(gBn + R1, sBn + 4096 + ldsw); }
                if (p == 1) { gl16(gBn + R2, sBn + 8192 + ldsw);
                              gl16(gBn + R3, sBn + 12288 + ldsw); }
                if (p == 2) { gl16(gAn,      sAn + ldsw);
                              gl16(gAn + R2, sAn + 8192 + ldsw); }
                if (p == 3) { gl16(gAn + R1, sAn + 4096 + ldsw);
                              gl16(gAn + R3, sAn + 12288 + ldsw); }
            }
            asm volatile("" ::: "memory");
            __builtin_amdgcn_s_barrier();
            asm volatile("" ::: "memory");
            __builtin_amdgcn_s_setprio(1);
#pragma unroll
            for (int ii = 0; ii < 2; ii++)
#pragma unroll
                for (int j = 0; j < 4; j++) {
                    acc[2*p+ii][j] = __builtin_amdgcn_mfma_f32_16x16x32_f16(
                        afr[ii][0], bfr[j][0], acc[2*p+ii][j], 0, 0, 0);
                    acc[2*p+ii][j] = __builtin_amdgcn_mfma_f32_16x16x32_f16(
                        afr[ii][1], bfr[j][1], acc[2*p+ii][j], 0, 0, 0);
                }
            __builtin_amdgcn_s_setprio(0);
            // counted vmcnt: ph1 guarantees A(t) r1,r3 (needed ph2/ph3);
            // ph3 guarantees B(t+1)+A(t+1) r0,r2 (needed next ph0), leaves 2.
            if (p == 1) {
                if (pref) asm volatile("s_waitcnt vmcnt(4)" ::: "memory");
                else      asm volatile("s_waitcnt vmcnt(0)" ::: "memory");
            }
            if (p == 3) {
                if (pref) asm volatile("s_waitcnt vmcnt(2)" ::: "memory");
                else      asm volatile("s_waitcnt vmcnt(0)" ::: "memory");
            }
            asm volatile("" ::: "memory");
            __builtin_amdgcn_s_barrier();
            asm volatile("" ::: "memory");
        }
    }

    // epilogue (C frag layout: col = lane&15, row = kq*4 + reg)
    const int row0 = m0 + wr * 128 + kq * 4;
    const int col0 = n0 + wc * 64 + fr;
    if constexpr (G1) {
        _Float16* Cq = (_Float16*)Cv;
#pragma unroll
        for (int j = 0; j < 4; j++) {
            const float bv = bias[col0 + j * 16];
#pragma unroll
            for (int i = 0; i < 8; i++) {
                size_t base = (size_t)(row0 + i * 16) * N + (col0 + j * 16);
#pragma unroll
                for (int r = 0; r < 4; r++) {
                    float v = fmaxf(acc[i][j][r] + bv, 0.0f);
                    Cq[base + (size_t)r * N] = (_Float16)q_e4m3_val(v);
                }
            }
        }
    } else {
        float* C = (float*)Cv;
#pragma unroll
        for (int j = 0; j < 4; j++) {
            const float bq = (float)(_Float16)bias[col0 + j * 16];
#pragma unroll
            for (int i = 0; i < 8; i++) {
                size_t base = (size_t)(row0 + i * 16) * N + (col0 + j * 16);
#pragma unroll
                for (int r = 0; r < 4; r++) {
                    float v = acc[i][j][r] + bq;
                    C[base + (size_t)r * N] = (float)(_Float16)v;
                }
            }
        }
    }
}

extern "C" void kernel_launch(void* const* d_in, const int* in_sizes, int n_in,
                              void* d_out, int out_size, void* d_ws, size_t ws_size,
                              hipStream_t stream) {
    const float* x  = (const float*)d_in[0];   // [16384,1024]
    const float* w1 = (const float*)d_in[1];   // [4096,1024]
    const float* b1 = (const float*)d_in[2];   // [4096]
    const float* w2 = (const float*)d_in[3];   // [1024,4096]
    const float* b2 = (const float*)d_in[4];   // [1024]
    float* out = (float*)d_out;

    // workspace layout (bytes):
    // hq  f16 [16384,4096] : 134,217,728
    // xh  f16 [16384,1024] :  33,554,432
    // w1h f16 [4096,1024]  :   8,388,608
    // wq  f16 [1024,4096]  :   8,388,608
    const size_t need = 134217728ull + 33554432ull + 2ull * 8388608ull;
    if (ws_size < need) return;  // fail visibly (output stays zero)

    char* ws = (char*)d_ws;
    _Float16* hq  = (_Float16*)ws;
    _Float16* xh  = (_Float16*)(ws + 134217728ull);
    _Float16* w1h = xh + 16777216;
    _Float16* wq  = w1h + 4194304;

    cvt_f16_kernel<<<16384, 256, 0, stream>>>(x, xh, 4194304);
    cvt_f16_kernel<<<4096, 256, 0, stream>>>(w1, w1h, 1048576);
    quant_e4m3_kernel<<<4096, 256, 0, stream>>>(w2, wq, 1048576);

    // GEMM1: M=16384, N=4096, K=1024 -> grid (16,64) = 1024 wg
    gemm_ffn<D_DIM, H_DIM, true ><<<dim3(H_DIM / 256, M_TOT / 256), 512, 0, stream>>>(xh, w1h, b1, hq);
    // GEMM2: M=16384, N=1024, K=4096 -> grid (4,64) = 256 wg (1 per CU)
    gemm_ffn<H_DIM, D_DIM, false><<<dim3(D_DIM / 256, M_TOT / 256), 512, 0, stream>>>(hq, wq, b2, out);
}

// Round 2
// 300.811 us; speedup vs baseline: 1.4491x; 1.0408x over previous
//
#include <hip/hip_runtime.h>
#include <stdint.h>

// FFN: x[16384,1024] -> relu(x@W1^T+b1)[16384,4096] -> q_e4m3 -> @W2^T+b2 -> q_e5m10
// Round 4: keep the 256x256/BK=64 counted-vmcnt template (round 3). Fix GEMM1's
// epilogue, which rocprof showed to be the real cost (VALUBusy 36%, WRITE 320MB
// vs 134MB ideal, MfmaUtil 31% ~= compute floor):
//   (a) division-free e4m3 quantization (bit-trick RNE, exact vs reference),
//   (b) coalesced f16 stores via swizzled LDS transpose of the C tile
//       (f16x8 16B/lane stores instead of scattered 2B stores).
// Numerics bit-identical: same MFMA order, same rounding values.

#define M_TOT 16384
#define D_DIM 1024
#define H_DIM 4096

typedef _Float16 f16x8 __attribute__((ext_vector_type(8)));
typedef _Float16 f16x4 __attribute__((ext_vector_type(4)));
typedef float f32x4 __attribute__((ext_vector_type(4)));

// global -> LDS direct copy, 16B per lane. LDS dest = wave-uniform base + lane*16.
__device__ __forceinline__ void gl16(const void* g, void* l) {
    __builtin_amdgcn_global_load_lds(
        (const __attribute__((address_space(1))) unsigned int*)(uintptr_t)g,
        (__attribute__((address_space(3))) unsigned int*)(unsigned int)(uintptr_t)l,
        16, 0, 0);
}

// e4m3 quantize (reference float_quantize exp=4 man=3: bias=7, min normal exp -6,
// subnormal quantum 2^-9, RNE, overflow->inf unreachable here: |x| << 240).
// Division-free:
//  normal (|x| >= 2^-6): RNE to 3 mantissa bits on fp32 bit pattern
//    (add 0x7FFFF + tie-bit then mask low 20 bits; carry into exponent is correct)
//  subnormal (|x| < 2^-6): quantum 2^-9; x*512 and *2^-9 are exact pow2 muls.
__device__ __forceinline__ float q_e4m3_any(float x) {
    uint32_t t = __float_as_uint(x);
    uint32_t s = t & 0x80000000u;
    uint32_t m = t & 0x7fffffffu;
    uint32_t tn = (m + 0x7ffffu + ((m >> 20) & 1u)) & 0xfff00000u;
    float qn = __uint_as_float(tn | s);
    float qs = rintf(x * 512.0f) * 0.001953125f;   // RNE, exact scales
    return __uint_as_float(m) < 0.015625f ? qs : qn;
}

// positive-input fast path (post-relu): no sign handling
__device__ __forceinline__ _Float16 q_e4m3_pos(float v) {
    uint32_t t = __float_as_uint(v);
    uint32_t tn = (t + 0x7ffffu + ((t >> 20) & 1u)) & 0xfff00000u;
    float qn = __uint_as_float(tn);
    float qs = rintf(v * 512.0f) * 0.001953125f;
    return (_Float16)(v < 0.015625f ? qs : qn);
}

// ---- pre-pass: fp32 -> f16 (RNE), vectorized x4 ----
__global__ __launch_bounds__(256) void cvt_f16_kernel(
    const float* __restrict__ in, _Float16* __restrict__ out, int n4)
{
    int i = blockIdx.x * 256 + threadIdx.x;
    if (i >= n4) return;
    float4 v = reinterpret_cast<const float4*>(in)[i];
    f16x4 hv = {(_Float16)v.x, (_Float16)v.y, (_Float16)v.z, (_Float16)v.w};
    reinterpret_cast<f16x4*>(out)[i] = hv;
}

// ---- pre-pass: fp32 -> e4m3 value stored as f16 (exactly representable) ----
__global__ __launch_bounds__(256) void quant_e4m3_kernel(
    const float* __restrict__ in, _Float16* __restrict__ outq, int n4)
{
    int i = blockIdx.x * 256 + threadIdx.x;
    if (i >= n4) return;
    float4 v = reinterpret_cast<const float4*>(in)[i];
    f16x4 q = {(_Float16)q_e4m3_any(v.x), (_Float16)q_e4m3_any(v.y),
               (_Float16)q_e4m3_any(v.z), (_Float16)q_e4m3_any(v.w)};
    reinterpret_cast<f16x4*>(outq)[i] = q;
}

// ---- unified 256x256 GEMM, NT (A[M,K], B[N,K] row-major), f16 MFMA fp32 acc ----
// G1=true : epilogue = +bias, relu, q_e4m3, LDS-transpose, coalesced f16 store
// G1=false: epilogue = +f16(bias), f16-roundtrip, store fp32 (already coalesced)
template<int K, int N, bool G1>
__global__ __launch_bounds__(512) void gemm_ffn(
    const _Float16* __restrict__ A, const _Float16* __restrict__ B,
    const float* __restrict__ bias, void* __restrict__ Cv)
{
    // 2 dbuf x [256 rows][64 K] f16 each for A and B: 128 KiB total.
    // Single array so the epilogue can reuse all 128 KiB as the C tile.
    __shared__ __align__(16) _Float16 smem[65536];
    _Float16* sA = smem;            // 2 x 16384
    _Float16* sB = smem + 32768;    // 2 x 16384

    const int tid  = threadIdx.x;
    const int lane = tid & 63;
    const int w    = tid >> 6;            // 8 waves: 2(M) x 4(N)
    const int wr   = w >> 2, wc = w & 3;  // per-wave C: 128 rows x 64 cols
    const int fr   = lane & 15, kq = lane >> 4;

    // T1: bijective XCD-chunked block swizzle (nwg % 8 == 0 for both GEMMs)
    constexpr int NBX = N / 256;
    constexpr int NWG = (M_TOT / 256) * NBX;
    constexpr int CPX = NWG / 8;
    int bid = blockIdx.y * NBX + blockIdx.x;
    bid = (bid & 7) * CPX + (bid >> 3);
    const int n0 = (bid % NBX) * 256;
    const int m0 = (bid / NBX) * 256;

    // staging: thread t covers LDS bytes t*16 of each 8KB round (64 rows x 128B).
    // source pre-swizzle: 16B-slot ^= (row & 7)  (involution, matches read XOR)
    const int srow = tid >> 3;                       // 0..63 row-in-round
    const int sseg = (tid & 7) ^ (srow & 7);         // swizzled 16B slot
    const _Float16* gA = A + (size_t)(m0 + srow) * K + sseg * 8;
    const _Float16* gB = B + (size_t)(n0 + srow) * K + sseg * 8;
    const int ldsw = w * 512;                        // wave offset in a round (f16)
    const size_t R1 = (size_t)64 * K, R2 = (size_t)128 * K, R3 = (size_t)192 * K;

    // fragment reads: row*64 + ((ks*4+kq) ^ (row&7))*8 ; row&7 == fr&7 always
    const int xorv = fr & 7;
    const int cA0 = (kq ^ xorv) * 8;         // ks=0 slot (elements)
    const int cA1 = ((kq + 4) ^ xorv) * 8;   // ks=1 slot
    const int aRow = wr * 128 + fr;
    const int bRow = wc * 64 + fr;

    f32x4 acc[8][4];
#pragma unroll
    for (int i = 0; i < 8; i++)
#pragma unroll
        for (int j = 0; j < 4; j++) acc[i][j] = (f32x4){0.f, 0.f, 0.f, 0.f};

    f16x8 bfr[4][2];

    constexpr int NK = K / 64;

    // prologue: stage tile 0 into buf0. Issue order must match in-loop order:
    // B r0,r1,r2,r3, A r0,r2, A r1,r3  -> vmcnt(2) leaves A r1,r3 in flight.
    gl16(gB,      sB + ldsw);
    gl16(gB + R1, sB + 4096 + ldsw);
    gl16(gB + R2, sB + 8192 + ldsw);
    gl16(gB + R3, sB + 12288 + ldsw);
    gl16(gA,      sA + ldsw);
    gl16(gA + R2, sA + 8192 + ldsw);
    gl16(gA + R1, sA + 4096 + ldsw);
    gl16(gA + R3, sA + 12288 + ldsw);
    asm volatile("s_waitcnt vmcnt(2)" ::: "memory");
    __builtin_amdgcn_s_barrier();
    asm volatile("" ::: "memory");

    for (int t = 0; t < NK; ++t) {
        const int c = t & 1;
        const _Float16* sAc = sA + c * 16384;
        const _Float16* sBc = sB + c * 16384;
        _Float16* sAn = sA + (c ^ 1) * 16384;
        _Float16* sBn = sB + (c ^ 1) * 16384;
        const bool pref = (t + 1 < NK);
        const _Float16* gAn = gA + (size_t)(t + 1) * 64;
        const _Float16* gBn = gB + (size_t)(t + 1) * 64;

#pragma unroll
        for (int p = 0; p < 4; ++p) {
            // ds_read this phase's A row-quadrant (+ all B frags at p==0)
            f16x8 afr[2][2];
#pragma unroll
            for (int ii = 0; ii < 2; ii++) {
                const _Float16* ra = sAc + (aRow + (2 * p + ii) * 16) * 64;
                afr[ii][0] = *(const f16x8*)(ra + cA0);
                afr[ii][1] = *(const f16x8*)(ra + cA1);
            }
            if (p == 0) {
#pragma unroll
                for (int j = 0; j < 4; j++) {
                    const _Float16* rb = sBc + (bRow + j * 16) * 64;
                    bfr[j][0] = *(const f16x8*)(rb + cA0);
                    bfr[j][1] = *(const f16x8*)(rb + cA1);
                }
            }
            // stage 2 rounds of next tile (block-uniform predicate)
            if (pref) {
                if (p == 0) { gl16(gBn,      sBn + ldsw);
                              gl16(gBn + R1, sBn + 4096 + ldsw); }
                if (p == 1) { gl16(gBn + R2, sBn + 8192 + ldsw);
                              gl16(gBn + R3, sBn + 12288 + ldsw); }
                if (p == 2) { gl16(gAn,      sAn + ldsw);
                              gl16(gAn + R2, sAn + 8192 + ldsw); }
                if (p == 3) { gl16(gAn + R1, sAn + 4096 + ldsw);
                              gl16(gAn + R3, sAn + 12288 + ldsw); }
            }
            asm volatile("" ::: "memory");
            __builtin_amdgcn_s_barrier();
            asm volatile("" ::: "memory");
            __builtin_amdgcn_s_setprio(1);
#pragma unroll
            for (int ii = 0; ii < 2; ii++)
#pragma unroll
                for (int j = 0; j < 4; j++) {
                    acc[2*p+ii][j] = __builtin_amdgcn_mfma_f32_16x16x32_f16(
                        afr[ii][0], bfr[j][0], acc[2*p+ii][j], 0, 0, 0);
                    acc[2*p+ii][j] = __builtin_amdgcn_mfma_f32_16x16x32_f16(
                        afr[ii][1], bfr[j][1], acc[2*p+ii][j], 0, 0, 0);
                }
            __builtin_amdgcn_s_setprio(0);
            // counted vmcnt: ph1 guarantees A(t) r1,r3 (needed ph2/ph3);
            // ph3 guarantees B(t+1)+A(t+1) r0,r2 (needed next ph0), leaves 2.
            if (p == 1) {
                if (pref) asm volatile("s_waitcnt vmcnt(4)" ::: "memory");
                else      asm volatile("s_waitcnt vmcnt(0)" ::: "memory");
            }
            if (p == 3) {
                if (pref) asm volatile("s_waitcnt vmcnt(2)" ::: "memory");
                else      asm volatile("s_waitcnt vmcnt(0)" ::: "memory");
            }
            asm volatile("" ::: "memory");
            __builtin_amdgcn_s_barrier();
            asm volatile("" ::: "memory");
        }
    }

    // epilogue (C frag layout: col = lane&15, row = kq*4 + reg)
    const int col0 = n0 + wc * 64 + fr;
    if constexpr (G1) {
        // quantize -> swizzled LDS C-tile (f16 [256][256]) -> coalesced stores.
        // 16B-slot swizzle: slot ^= (row&7) ^ ((row>>3)&1)  (2-way residual only)
        _Float16* Cq = (_Float16*)Cv;
        float bv[4];
#pragma unroll
        for (int j = 0; j < 4; j++) bv[j] = bias[col0 + j * 16];
        const int sub = (fr & 7) * 2;             // byte within 16B slot
        const int slotbase = wc * 8 + (fr >> 3);  // + j*2
        const int rowbase = wr * 128 + kq * 4;    // + i*16 + r
#pragma unroll
        for (int i = 0; i < 8; i++) {
            const int trow0 = rowbase + i * 16;
#pragma unroll
            for (int r = 0; r < 4; r++) {
                const int trow = trow0 + r;
                const int swz = (((kq & 1) * 4 + r)) ^ (kq >> 1);  // == (trow&7)^((trow>>3)&1)
#pragma unroll
                for (int j = 0; j < 4; j++) {
                    float v = fmaxf(acc[i][j][r] + bv[j], 0.0f);
                    _Float16 q = q_e4m3_pos(v);
                    int byte = trow * 512 + (((slotbase + j * 2) ^ swz) << 4) + sub;
                    *(_Float16*)((char*)smem + byte) = q;
                }
            }
        }
        __syncthreads();
#pragma unroll
        for (int cch = 0; cch < 16; cch++) {
            int flat = cch * 512 + tid;          // 16B-chunk index, 8192 total
            int row  = flat >> 5;                // 0..255
            int slot = flat & 31;
            int swz  = (row & 7) ^ ((row >> 3) & 1);
            f16x8 v8 = *(const f16x8*)((char*)smem + row * 512 + ((slot ^ swz) << 4));
            *(f16x8*)(Cq + (size_t)(m0 + row) * N + n0 + slot * 8) = v8;
        }
    } else {
        const int row0 = m0 + wr * 128 + kq * 4;
        float* C = (float*)Cv;
#pragma unroll
        for (int j = 0; j < 4; j++) {
            const float bq = (float)(_Float16)bias[col0 + j * 16];
#pragma unroll
            for (int i = 0; i < 8; i++) {
                size_t base = (size_t)(row0 + i * 16) * N + (col0 + j * 16);
#pragma unroll
                for (int r = 0; r < 4; r++) {
                    float v = acc[i][j][r] + bq;
                    C[base + (size_t)r * N] = (float)(_Float16)v;
                }
            }
        }
    }
}

extern "C" void kernel_launch(void* const* d_in, const int* in_sizes, int n_in,
                              void* d_out, int out_size, void* d_ws, size_t ws_size,
                              hipStream_t stream) {
    const float* x  = (const float*)d_in[0];   // [16384,1024]
    const float* w1 = (const float*)d_in[1];   // [4096,1024]
    const float* b1 = (const float*)d_in[2];   // [4096]
    const float* w2 = (const float*)d_in[3];   // [1024,4096]
    const float* b2 = (const float*)d_in[4];   // [1024]
    float* out = (float*)d_out;

    // workspace layout (bytes):
    // hq  f16 [16384,4096] : 134,217,728
    // xh  f16 [16384,1024] :  33,554,432
    // w1h f16 [4096,1024]  :   8,388,608
    // wq  f16 [1024,4096]  :   8,388,608
    const size_t need = 134217728ull + 33554432ull + 2ull * 8388608ull;
    if (ws_size < need) return;  // fail visibly (output stays zero)

    char* ws = (char*)d_ws;
    _Float16* hq  = (_Float16*)ws;
    _Float16* xh  = (_Float16*)(ws + 134217728ull);
    _Float16* w1h = xh + 16777216;
    _Float16* wq  = w1h + 4194304;

    cvt_f16_kernel<<<16384, 256, 0, stream>>>(x, xh, 4194304);
    cvt_f16_kernel<<<4096, 256, 0, stream>>>(w1, w1h, 1048576);
    quant_e4m3_kernel<<<4096, 256, 0, stream>>>(w2, wq, 1048576);

    // GEMM1: M=16384, N=4096, K=1024 -> grid (16,64) = 1024 wg
    gemm_ffn<D_DIM, H_DIM, true ><<<dim3(H_DIM / 256, M_TOT / 256), 512, 0, stream>>>(xh, w1h, b1, hq);
    // GEMM2: M=16384, N=1024, K=4096 -> grid (4,64) = 256 wg (1 per CU)
    gemm_ffn<H_DIM, D_DIM, false><<<dim3(D_DIM / 256, M_TOT / 256), 512, 0, stream>>>(hq, wq, b2, out);
}

// Round 3
// 298.691 us; speedup vs baseline: 1.4594x; 1.0071x over previous
//
#include <hip/hip_runtime.h>
#include <stdint.h>

// FFN: x[16384,1024] -> relu(x@W1^T+b1)[16384,4096] -> q_e4m3 -> @W2^T+b2 -> q_e5m10
// Round 5: deepen the prefetch pipeline. rocprof showed both GEMMs at ~4400
// cyc/tile vs 2060 MFMA floor (46%); the m201 reference with identical geometry
// reaches 62% (~3300, LDS-traffic structural floor). Diagnosis: old staging
// order (2,2,2,2) made ph3's vmcnt(2) wait on loads issued only 1 phase
// (~600cy) earlier vs ~900cy HBM latency -> per-tile stall. New order 3,3,1,1:
// every vmcnt target is >=3 phases (~1800cy) old, fully covering HBM latency.
//   ph0: ds B(t)+A(t)q0; stage B(t+1)r0,r1,r2 ; bar; MFMA16; bar
//   ph1: ds A(t)q1;      stage B(t+1)r3,A r0,r2; bar; MFMA16; vmcnt(6); bar
//   ph2: ds A(t)q2;      stage A(t+1)r1;        bar; MFMA16; bar
//   ph3: ds A(t)q3;      stage A(t+1)r3;        bar; MFMA16; vmcnt(2); bar
// Entry invariant per tile: outstanding = {A(t)r1, A(t)r3}; ph1's vmcnt(6)
// drains exactly those; ph3's vmcnt(2) drains next tile's ph0 needs.
// Epilogue (round 4) unchanged: division-free e4m3 + swizzled LDS transpose.

#define M_TOT 16384
#define D_DIM 1024
#define H_DIM 4096

typedef _Float16 f16x8 __attribute__((ext_vector_type(8)));
typedef _Float16 f16x4 __attribute__((ext_vector_type(4)));
typedef float f32x4 __attribute__((ext_vector_type(4)));

// global -> LDS direct copy, 16B per lane. LDS dest = wave-uniform base + lane*16.
__device__ __forceinline__ void gl16(const void* g, void* l) {
    __builtin_amdgcn_global_load_lds(
        (const __attribute__((address_space(1))) unsigned int*)(uintptr_t)g,
        (__attribute__((address_space(3))) unsigned int*)(unsigned int)(uintptr_t)l,
        16, 0, 0);
}

// e4m3 quantize (reference float_quantize exp=4 man=3: bias=7, min normal exp -6,
// subnormal quantum 2^-9, RNE, overflow->inf unreachable here: |x| << 240).
__device__ __forceinline__ float q_e4m3_any(float x) {
    uint32_t t = __float_as_uint(x);
    uint32_t s = t & 0x80000000u;
    uint32_t m = t & 0x7fffffffu;
    uint32_t tn = (m + 0x7ffffu + ((m >> 20) & 1u)) & 0xfff00000u;
    float qn = __uint_as_float(tn | s);
    float qs = rintf(x * 512.0f) * 0.001953125f;   // RNE, exact scales
    return __uint_as_float(m) < 0.015625f ? qs : qn;
}

// positive-input fast path (post-relu): no sign handling
__device__ __forceinline__ _Float16 q_e4m3_pos(float v) {
    uint32_t t = __float_as_uint(v);
    uint32_t tn = (t + 0x7ffffu + ((t >> 20) & 1u)) & 0xfff00000u;
    float qn = __uint_as_float(tn);
    float qs = rintf(v * 512.0f) * 0.001953125f;
    return (_Float16)(v < 0.015625f ? qs : qn);
}

// ---- pre-pass: fp32 -> f16 (RNE), vectorized x4 ----
__global__ __launch_bounds__(256) void cvt_f16_kernel(
    const float* __restrict__ in, _Float16* __restrict__ out, int n4)
{
    int i = blockIdx.x * 256 + threadIdx.x;
    if (i >= n4) return;
    float4 v = reinterpret_cast<const float4*>(in)[i];
    f16x4 hv = {(_Float16)v.x, (_Float16)v.y, (_Float16)v.z, (_Float16)v.w};
    reinterpret_cast<f16x4*>(out)[i] = hv;
}

// ---- pre-pass: fp32 -> e4m3 value stored as f16 (exactly representable) ----
__global__ __launch_bounds__(256) void quant_e4m3_kernel(
    const float* __restrict__ in, _Float16* __restrict__ outq, int n4)
{
    int i = blockIdx.x * 256 + threadIdx.x;
    if (i >= n4) return;
    float4 v = reinterpret_cast<const float4*>(in)[i];
    f16x4 q = {(_Float16)q_e4m3_any(v.x), (_Float16)q_e4m3_any(v.y),
               (_Float16)q_e4m3_any(v.z), (_Float16)q_e4m3_any(v.w)};
    reinterpret_cast<f16x4*>(outq)[i] = q;
}

// ---- unified 256x256 GEMM, NT (A[M,K], B[N,K] row-major), f16 MFMA fp32 acc ----
// G1=true : epilogue = +bias, relu, q_e4m3, LDS-transpose, coalesced f16 store
// G1=false: epilogue = +f16(bias), f16-roundtrip, store fp32 (already coalesced)
template<int K, int N, bool G1>
__global__ __launch_bounds__(512) void gemm_ffn(
    const _Float16* __restrict__ A, const _Float16* __restrict__ B,
    const float* __restrict__ bias, void* __restrict__ Cv)
{
    // 2 dbuf x [256 rows][64 K] f16 each for A and B: 128 KiB total.
    // Single array so the epilogue can reuse all 128 KiB as the C tile.
    __shared__ __align__(16) _Float16 smem[65536];
    _Float16* sA = smem;            // 2 x 16384
    _Float16* sB = smem + 32768;    // 2 x 16384

    const int tid  = threadIdx.x;
    const int lane = tid & 63;
    const int w    = tid >> 6;            // 8 waves: 2(M) x 4(N)
    const int wr   = w >> 2, wc = w & 3;  // per-wave C: 128 rows x 64 cols
    const int fr   = lane & 15, kq = lane >> 4;

    // T1: bijective XCD-chunked block swizzle (nwg % 8 == 0 for both GEMMs)
    constexpr int NBX = N / 256;
    constexpr int NWG = (M_TOT / 256) * NBX;
    constexpr int CPX = NWG / 8;
    int bid = blockIdx.y * NBX + blockIdx.x;
    bid = (bid & 7) * CPX + (bid >> 3);
    const int n0 = (bid % NBX) * 256;
    const int m0 = (bid / NBX) * 256;

    // staging: thread t covers LDS bytes t*16 of each 8KB round (64 rows x 128B).
    // source pre-swizzle: 16B-slot ^= (row & 7)  (involution, matches read XOR)
    const int srow = tid >> 3;                       // 0..63 row-in-round
    const int sseg = (tid & 7) ^ (srow & 7);         // swizzled 16B slot
    const _Float16* gA = A + (size_t)(m0 + srow) * K + sseg * 8;
    const _Float16* gB = B + (size_t)(n0 + srow) * K + sseg * 8;
    const int ldsw = w * 512;                        // wave offset in a round (f16)
    const size_t R1 = (size_t)64 * K, R2 = (size_t)128 * K, R3 = (size_t)192 * K;

    // fragment reads: row*64 + ((ks*4+kq) ^ (row&7))*8 ; row&7 == fr&7 always
    const int xorv = fr & 7;
    const int cA0 = (kq ^ xorv) * 8;         // ks=0 slot (elements)
    const int cA1 = ((kq + 4) ^ xorv) * 8;   // ks=1 slot
    const int aRow = wr * 128 + fr;
    const int bRow = wc * 64 + fr;

    f32x4 acc[8][4];
#pragma unroll
    for (int i = 0; i < 8; i++)
#pragma unroll
        for (int j = 0; j < 4; j++) acc[i][j] = (f32x4){0.f, 0.f, 0.f, 0.f};

    f16x8 bfr[4][2];

    constexpr int NK = K / 64;

    // prologue: stage tile 0 into buf0, ending with A r1,A r3 so the steady
    // entry invariant (outstanding = {A r1, A r3}) holds from tile 0.
    gl16(gB,      sB + ldsw);
    gl16(gB + R1, sB + 4096 + ldsw);
    gl16(gB + R2, sB + 8192 + ldsw);
    gl16(gB + R3, sB + 12288 + ldsw);
    gl16(gA,      sA + ldsw);
    gl16(gA + R2, sA + 8192 + ldsw);
    gl16(gA + R1, sA + 4096 + ldsw);
    gl16(gA + R3, sA + 12288 + ldsw);
    asm volatile("s_waitcnt vmcnt(2)" ::: "memory");
    __builtin_amdgcn_s_barrier();
    asm volatile("" ::: "memory");

    for (int t = 0; t < NK; ++t) {
        const int c = t & 1;
        const _Float16* sAc = sA + c * 16384;
        const _Float16* sBc = sB + c * 16384;
        _Float16* sAn = sA + (c ^ 1) * 16384;
        _Float16* sBn = sB + (c ^ 1) * 16384;
        const bool pref = (t + 1 < NK);
        const _Float16* gAn = gA + (size_t)(t + 1) * 64;
        const _Float16* gBn = gB + (size_t)(t + 1) * 64;

#pragma unroll
        for (int p = 0; p < 4; ++p) {
            // ds_read this phase's A row-quadrant (+ all B frags at p==0)
            f16x8 afr[2][2];
#pragma unroll
            for (int ii = 0; ii < 2; ii++) {
                const _Float16* ra = sAc + (aRow + (2 * p + ii) * 16) * 64;
                afr[ii][0] = *(const f16x8*)(ra + cA0);
                afr[ii][1] = *(const f16x8*)(ra + cA1);
            }
            if (p == 0) {
#pragma unroll
                for (int j = 0; j < 4; j++) {
                    const _Float16* rb = sBc + (bRow + j * 16) * 64;
                    bfr[j][0] = *(const f16x8*)(rb + cA0);
                    bfr[j][1] = *(const f16x8*)(rb + cA1);
                }
            }
            // stage next tile, front-loaded 3,3,1,1 (block-uniform predicate):
            // every later vmcnt target is >=3 phases old -> HBM latency covered.
            if (pref) {
                if (p == 0) { gl16(gBn,      sBn + ldsw);
                              gl16(gBn + R1, sBn + 4096 + ldsw);
                              gl16(gBn + R2, sBn + 8192 + ldsw); }
                if (p == 1) { gl16(gBn + R3, sBn + 12288 + ldsw);
                              gl16(gAn,      sAn + ldsw);
                              gl16(gAn + R2, sAn + 8192 + ldsw); }
                if (p == 2) { gl16(gAn + R1, sAn + 4096 + ldsw); }
                if (p == 3) { gl16(gAn + R3, sAn + 12288 + ldsw); }
            }
            asm volatile("" ::: "memory");
            __builtin_amdgcn_s_barrier();
            asm volatile("" ::: "memory");
            __builtin_amdgcn_s_setprio(1);
#pragma unroll
            for (int ii = 0; ii < 2; ii++)
#pragma unroll
                for (int j = 0; j < 4; j++) {
                    acc[2*p+ii][j] = __builtin_amdgcn_mfma_f32_16x16x32_f16(
                        afr[ii][0], bfr[j][0], acc[2*p+ii][j], 0, 0, 0);
                    acc[2*p+ii][j] = __builtin_amdgcn_mfma_f32_16x16x32_f16(
                        afr[ii][1], bfr[j][1], acc[2*p+ii][j], 0, 0, 0);
                }
            __builtin_amdgcn_s_setprio(0);
            // counted vmcnt: ph1's vmcnt(6) drains exactly {A(t)r1, A(t)r3}
            // (issued 3-4 phases ago); ph3's vmcnt(2) drains next-ph0's needs
            // (B(t+1)r0-3, A(t+1)r0,r2 — all issued >=3 phases ago).
            if (p == 1) {
                if (pref) asm volatile("s_waitcnt vmcnt(6)" ::: "memory");
                else      asm volatile("s_waitcnt vmcnt(0)" ::: "memory");
            }
            if (p == 3) {
                if (pref) asm volatile("s_waitcnt vmcnt(2)" ::: "memory");
                else      asm volatile("s_waitcnt vmcnt(0)" ::: "memory");
            }
            asm volatile("" ::: "memory");
            __builtin_amdgcn_s_barrier();
            asm volatile("" ::: "memory");
        }
    }

    // epilogue (C frag layout: col = lane&15, row = kq*4 + reg)
    const int col0 = n0 + wc * 64 + fr;
    if constexpr (G1) {
        // quantize -> swizzled LDS C-tile (f16 [256][256]) -> coalesced stores.
        // 16B-slot swizzle: slot ^= (row&7) ^ ((row>>3)&1)  (2-way residual only)
        _Float16* Cq = (_Float16*)Cv;
        float bv[4];
#pragma unroll
        for (int j = 0; j < 4; j++) bv[j] = bias[col0 + j * 16];
        const int sub = (fr & 7) * 2;             // byte within 16B slot
        const int slotbase = wc * 8 + (fr >> 3);  // + j*2
        const int rowbase = wr * 128 + kq * 4;    // + i*16 + r
#pragma unroll
        for (int i = 0; i < 8; i++) {
            const int trow0 = rowbase + i * 16;
#pragma unroll
            for (int r = 0; r < 4; r++) {
                const int trow = trow0 + r;
                const int swz = (((kq & 1) * 4 + r)) ^ (kq >> 1);  // == (trow&7)^((trow>>3)&1)
#pragma unroll
                for (int j = 0; j < 4; j++) {
                    float v = fmaxf(acc[i][j][r] + bv[j], 0.0f);
                    _Float16 q = q_e4m3_pos(v);
                    int byte = trow * 512 + (((slotbase + j * 2) ^ swz) << 4) + sub;
                    *(_Float16*)((char*)smem + byte) = q;
                }
            }
        }
        __syncthreads();
#pragma unroll
        for (int cch = 0; cch < 16; cch++) {
            int flat = cch * 512 + tid;          // 16B-chunk index, 8192 total
            int row  = flat >> 5;                // 0..255
            int slot = flat & 31;
            int swz  = (row & 7) ^ ((row >> 3) & 1);
            f16x8 v8 = *(const f16x8*)((char*)smem + row * 512 + ((slot ^ swz) << 4));
            *(f16x8*)(Cq + (size_t)(m0 + row) * N + n0 + slot * 8) = v8;
        }
    } else {
        const int row0 = m0 + wr * 128 + kq * 4;
        float* C = (float*)Cv;
#pragma unroll
        for (int j = 0; j < 4; j++) {
            const float bq = (float)(_Float16)bias[col0 + j * 16];
#pragma unroll
            for (int i = 0; i < 8; i++) {
                size_t base = (size_t)(row0 + i * 16) * N + (col0 + j * 16);
#pragma unroll
                for (int r = 0; r < 4; r++) {
                    float v = acc[i][j][r] + bq;
                    C[base + (size_t)r * N] = (float)(_Float16)v;
                }
            }
        }
    }
}

extern "C" void kernel_launch(void* const* d_in, const int* in_sizes, int n_in,
                              void* d_out, int out_size, void* d_ws, size_t ws_size,
                              hipStream_t stream) {
    const float* x  = (const float*)d_in[0];   // [16384,1024]
    const float* w1 = (const float*)d_in[1];   // [4096,1024]
    const float* b1 = (const float*)d_in[2];   // [4096]
    const float* w2 = (const float*)d_in[3];   // [1024,4096]
    const float* b2 = (const float*)d_in[4];   // [1024]
    float* out = (float*)d_out;

    // workspace layout (bytes):
    // hq  f16 [16384,4096] : 134,217,728
    // xh  f16 [16384,1024] :  33,554,432
    // w1h f16 [4096,1024]  :   8,388,608
    // wq  f16 [1024,4096]  :   8,388,608
    const size_t need = 134217728ull + 33554432ull + 2ull * 8388608ull;
    if (ws_size < need) return;  // fail visibly (output stays zero)

    char* ws = (char*)d_ws;
    _Float16* hq  = (_Float16*)ws;
    _Float16* xh  = (_Float16*)(ws + 134217728ull);
    _Float16* w1h = xh + 16777216;
    _Float16* wq  = w1h + 4194304;

    cvt_f16_kernel<<<16384, 256, 0, stream>>>(x, xh, 4194304);
    cvt_f16_kernel<<<4096, 256, 0, stream>>>(w1, w1h, 1048576);
    quant_e4m3_kernel<<<4096, 256, 0, stream>>>(w2, wq, 1048576);

    // GEMM1: M=16384, N=4096, K=1024 -> grid (16,64) = 1024 wg
    gemm_ffn<D_DIM, H_DIM, true ><<<dim3(H_DIM / 256, M_TOT / 256), 512, 0, stream>>>(xh, w1h, b1, hq);
    // GEMM2: M=16384, N=1024, K=4096 -> grid (4,64) = 256 wg (1 per CU)
    gemm_ffn<H_DIM, D_DIM, false><<<dim3(D_DIM / 256, M_TOT / 256), 512, 0, stream>>>(hq, wq, b2, out);
}